// Round 1
// baseline (158.537 us; speedup 1.0000x reference)
//
#include <hip/hip_runtime.h>

#define VOCAB 50000
#define EMBED 256
#define NB    16
#define NC    64
#define NS    512
#define UNK   1

// ---- bf16 fast path geometry (R8) ----
// CTILE=16 c's per block, JT=32 j-tiles of JLEN=16 -> 2048 blocks.
// No qt LDS staging (it saved no global traffic; each q row is read once per
// block either way). uint4 gathers: 32 lanes cover one 512-B bf16 row, so one
// wave-instruction fetches TWO rows (half-wave per row) -> half the VMEM insts.
// Register-budgeted inner loop + __launch_bounds__(256,8) targets <=64 VGPR,
// ~1.4 KB LDS -> 8 blocks/CU = 32 waves/CU (was 4 blocks / 16 waves, LDS-capped).
#define CTILE 16
#define JT    32
#define JLEN  (NS / JT)                                     // 16
#define BF_TABLE_BYTES ((size_t)VOCAB * EMBED * 2)          // 25,600,000
#define PARTIAL_ELEMS  (JT * NB * NC)                       // 32768

__device__ __forceinline__ unsigned short f2bf_rne(float f) {
    unsigned int u = __float_as_uint(f);
    u = (u + 0x7fffu + ((u >> 16) & 1u)) >> 16;             // round-nearest-even
    return (unsigned short)u;
}

// Stream-convert emb f32 -> bf16 table in ws. 1.6M threads x 8 elems.
__global__ __launch_bounds__(256) void convert_kernel(
    const float* __restrict__ emb, unsigned int* __restrict__ bf)
{
    const size_t t = (size_t)blockIdx.x * 256 + threadIdx.x;
    const float4* __restrict__ e4 = (const float4*)emb;
    const float4 a = e4[t * 2];
    const float4 b = e4[t * 2 + 1];
    uint4 r;
    r.x = (unsigned int)f2bf_rne(a.x) | ((unsigned int)f2bf_rne(a.y) << 16);
    r.y = (unsigned int)f2bf_rne(a.z) | ((unsigned int)f2bf_rne(a.w) << 16);
    r.z = (unsigned int)f2bf_rne(b.x) | ((unsigned int)f2bf_rne(b.y) << 16);
    r.w = (unsigned int)f2bf_rne(b.z) | ((unsigned int)f2bf_rne(b.w) << 16);
    ((uint4*)bf)[t] = r;
}

// Gather-bound scores. Grid = NB * (NC/CTILE) * JT = 2048 blocks, 256 thr.
// Each wave handles j = wave, wave+4, ... ; per j: two dwordx4 query loads
// (f32, L3-resident after convert) + 8 dual-row uint4 bf16 gathers.
__global__ __launch_bounds__(256, 8) void scores_bf_kernel(
    const int* __restrict__ src, const int* __restrict__ q,
    const float* __restrict__ emb, const unsigned int* __restrict__ bf,
    float* __restrict__ partial)
{
    const int x  = blockIdx.x;
    const int jt = x & (JT - 1);
    const int ct = (x >> 5) & (NC / CTILE - 1);
    const int b  = x >> 7;
    const int c0 = ct * CTILE;
    const int j0 = jt * JLEN;

    const int tid  = threadIdx.x;
    const int wave = tid >> 6;
    const int lane = tid & 63;
    const int half = lane >> 5;         // which of the 2 rows this lane serves
    const int hl   = lane & 31;         // covers elements [8*hl, 8*hl+7]

    const float4* __restrict__ emb4 = (const float4*)emb;
    const uint4*  __restrict__ bft  = (const uint4*)bf;     // 32 uint4 per row
    const int* __restrict__ qrow = q + (size_t)b * NS;
    const int* __restrict__ srow = src + ((size_t)b * NC + c0) * NS;

    __shared__ int sids[CTILE][JLEN];   // 1 KB clamped source ids
    __shared__ int qids[JLEN];
    __shared__ int nnz_sh;

    if (tid < 64) {                                  // wave 0
        const int qv = (tid < JLEN) ? qrow[j0 + tid] : 0;
        if (tid < JLEN) qids[tid] = (qv >= VOCAB) ? UNK : qv;
        const unsigned long long bal = __ballot(qv > 0);
        if (tid == 0) nnz_sh = __popcll(bal);        // contiguous prefix in tile
    }
    {   // 256 tile ids, 1 per thread
        const int i = tid >> 4;                      // c within tile (0..15)
        const int j = tid & (JLEN - 1);
        const int sv = srow[(size_t)i * NS + j0 + j];
        sids[i][j] = (sv >= VOCAB) ? UNK : sv;
    }
    __syncthreads();

    const int nnz = nnz_sh;

    float acc[8];                       // acc[i] <-> c = c0 + i + 8*half
#pragma unroll
    for (int i = 0; i < 8; i++) acc[i] = 0.f;

    for (int j = wave; j < nnz; j += 4) {
        const int qid = qids[j];
        const float4 q0 = emb4[(size_t)qid * (EMBED / 4) + hl * 2];
        const float4 q1 = emb4[(size_t)qid * (EMBED / 4) + hl * 2 + 1];
        // two chunks of 4 row-pairs keeps live gather buffers at 16 VGPR
#pragma unroll
        for (int mm = 0; mm < 2; mm++) {
            uint4 g[4];
#pragma unroll
            for (int k = 0; k < 4; k++) {
                const int cc = mm * 4 + k + 8 * half;
                g[k] = bft[(size_t)sids[cc][j] * 32 + hl];
            }
#pragma unroll
            for (int k = 0; k < 4; k++) {
                const float f0 = __uint_as_float(g[k].x << 16);
                const float f1 = __uint_as_float(g[k].x & 0xffff0000u);
                const float f2 = __uint_as_float(g[k].y << 16);
                const float f3 = __uint_as_float(g[k].y & 0xffff0000u);
                const float f4 = __uint_as_float(g[k].z << 16);
                const float f5 = __uint_as_float(g[k].z & 0xffff0000u);
                const float f6 = __uint_as_float(g[k].w << 16);
                const float f7 = __uint_as_float(g[k].w & 0xffff0000u);
                acc[mm * 4 + k] += f0 * q0.x + f1 * q0.y + f2 * q0.z + f3 * q0.w
                                 + f4 * q1.x + f5 * q1.y + f6 * q1.z + f7 * q1.w;
            }
        }
    }

    // reduce within each 32-lane half (each half owns distinct c's)
#pragma unroll
    for (int off = 16; off > 0; off >>= 1)
#pragma unroll
        for (int i = 0; i < 8; i++)
            acc[i] += __shfl_down(acc[i], off, 32);

    __shared__ float red[4][CTILE];
    if (hl == 0)
#pragma unroll
        for (int i = 0; i < 8; i++) red[wave][i + 8 * half] = acc[i];
    __syncthreads();

    if (tid < CTILE) {
        const float s = red[0][tid] + red[1][tid] + red[2][tid] + red[3][tid];
        partial[(size_t)jt * (NB * NC) + b * NC + c0 + tid] = s;
    }
}

// ---- f32 fallback (proven R5 path), JT=8/JLEN=64, CTILE=8 ----
__global__ __launch_bounds__(256) void scores_f32_kernel(
    const int* __restrict__ src, const int* __restrict__ q,
    const float* __restrict__ emb, float* __restrict__ partial)
{
    const int x  = blockIdx.x;
    const int jt = x & 7;
    const int ct = (x >> 3) & 7;
    const int b  = x >> 6;
    const int c0 = ct * 8;
    const int j0 = jt * 64;

    const int tid = threadIdx.x, wave = tid >> 6, lane = tid & 63;
    const float4* __restrict__ emb4 = (const float4*)emb;
    const int* __restrict__ qrow = q + (size_t)b * NS;
    const int* __restrict__ srow = src + ((size_t)b * NC + c0) * NS;

    float acc[8];
#pragma unroll
    for (int i = 0; i < 8; i++) acc[i] = 0.f;

    for (int j = j0 + wave; j < j0 + 64; j += 4) {
        const int qv = qrow[j];
        if (qv > 0) {
            const int qid = (qv >= VOCAB) ? UNK : qv;
            const float4 eq = emb4[(size_t)qid * (EMBED / 4) + lane];
            float4 a[8];
#pragma unroll
            for (int i = 0; i < 8; i++) {
                const int sv = srow[(size_t)i * NS + j];
                a[i] = emb4[(size_t)((sv >= VOCAB) ? UNK : sv) * (EMBED / 4) + lane];
            }
#pragma unroll
            for (int i = 0; i < 8; i++)
                acc[i] += a[i].x * eq.x + a[i].y * eq.y + a[i].z * eq.z + a[i].w * eq.w;
        }
    }
#pragma unroll
    for (int off = 32; off > 0; off >>= 1)
#pragma unroll
        for (int i = 0; i < 8; i++)
            acc[i] += __shfl_down(acc[i], off, 64);

    __shared__ float red[4][8];
    if (lane == 0)
#pragma unroll
        for (int i = 0; i < 8; i++) red[wave][i] = acc[i];
    __syncthreads();
    if (tid < 8)
        partial[(size_t)jt * (NB * NC) + b * NC + c0 + tid] =
            red[0][tid] + red[1][tid] + red[2][tid] + red[3][tid];
}

// One block per b. Wave 0: sum jtn partials -> softmax -> sims + argmax;
// then all 256 threads copy the winning source row as f32.
__global__ __launch_bounds__(256) void finalize_kernel(
    const float* __restrict__ partial, const int* __restrict__ src,
    float* __restrict__ out, int jtn)
{
    const int b = blockIdx.x, tid = threadIdx.x;
    __shared__ int top_sh;

    if (tid < 64) {
        float s = 0.f;
        for (int t = 0; t < jtn; t++)
            s += partial[(size_t)t * (NB * NC) + b * NC + tid];

        float m = s;
#pragma unroll
        for (int off = 32; off > 0; off >>= 1)
            m = fmaxf(m, __shfl_xor(m, off, 64));
        const float e = expf(s - m);
        float sum = e;
#pragma unroll
        for (int off = 32; off > 0; off >>= 1)
            sum += __shfl_xor(sum, off, 64);

        out[NB * NS + b * NC + tid] = e / sum;       // sims after 8192 ids

        const unsigned long long ballot = __ballot(s == m);
        if (tid == 0) top_sh = __ffsll(ballot) - 1;  // first occurrence
    }
    __syncthreads();

    const int top = top_sh;
    const int* __restrict__ srow = src + ((size_t)b * NC + top) * NS;
    for (int j = tid; j < NS; j += 256)
        out[b * NS + j] = (float)srow[j];
}

extern "C" void kernel_launch(void* const* d_in, const int* in_sizes, int n_in,
                              void* d_out, int out_size, void* d_ws, size_t ws_size,
                              hipStream_t stream) {
    const int*   src = (const int*)d_in[0];    // [NB*NC, NS] int32
    const int*   q   = (const int*)d_in[1];    // [NB, NS] int32
    const float* emb = (const float*)d_in[3];  // [VOCAB, EMBED] f32
    float* out = (float*)d_out;                // 8192 out_sources + 1024 sims (f32)

    if (ws_size >= BF_TABLE_BYTES + PARTIAL_ELEMS * sizeof(float)) {
        unsigned int* bf = (unsigned int*)d_ws;
        float* partial = (float*)((char*)d_ws + BF_TABLE_BYTES);
        convert_kernel<<<VOCAB * EMBED / 2048, 256, 0, stream>>>(emb, bf);
        scores_bf_kernel<<<NB * (NC / CTILE) * JT, 256, 0, stream>>>(src, q, emb, bf, partial);
        finalize_kernel<<<NB, 256, 0, stream>>>(partial, src, out, JT);
    } else {
        float* partial = (float*)d_ws;         // 8192 floats
        scores_f32_kernel<<<NB * 8 * 8, 256, 0, stream>>>(src, q, emb, partial);
        finalize_kernel<<<NB, 256, 0, stream>>>(partial, src, out, 8);
    }
}